// Round 11
// baseline (313.472 us; speedup 1.0000x reference)
//
#include <hip/hip_runtime.h>
#include <hip/hip_bf16.h>

#define N_NODES 20000
#define N_REL 32
#define HID 128
#define EMB 16
#define N_EDGES 600000
#define NB (N_NODES * N_REL)   // 640000 bins

typedef __attribute__((ext_vector_type(8))) short  bf8v;   // 8 bf16 (MFMA A/B frag)
typedef __attribute__((ext_vector_type(8))) unsigned short us8v; // 16-byte unit
typedef __attribute__((ext_vector_type(4))) unsigned short us4v; // 8-byte unit
typedef __attribute__((ext_vector_type(4))) float  f4v;    // MFMA C/D frag

__device__ __forceinline__ unsigned short f2b(float f) {
    __hip_bfloat16 h = __float2bfloat16(f);
    return __builtin_bit_cast(unsigned short, h);
}
__device__ __forceinline__ float b2f(unsigned short u) {
    unsigned int x = ((unsigned int)u) << 16;
    return __builtin_bit_cast(float, x);
}

// Barrier with LDS-only drain (global prefetches stay in flight).
__device__ __forceinline__ void lds_barrier() {
    asm volatile("s_waitcnt lgkmcnt(0)\n\ts_barrier" ::: "memory");
}

// ======== pre-pass (VECTORIZED): histogram + fragment-major bf16 layouts ====
// Unified B layout [kb][ct8][512] where kb is a global K-block (32 k's).
//  - W2: kb = r*4 + ks                      (256 kb)
//  - W1: kb packs TWO relations per K-block (k<16 -> rel 2kb, k>=16 -> rel 2kb+1)
//  - xb: raw bf16 copy of x, 16 shorts/row (no zero pad).
#define V_W2  (N_REL * HID * HID / 4)   // 262144
#define V_XB  (N_NODES * EMB / 4)       // 80000
#define V_W1  (N_REL * EMB * HID / 4)   // 16384
#define V_R1  (HID * 32 / 4)            // 1024
#define V_R2  (HID * HID / 4)           // 4096
#define V_HIST (N_EDGES / 2)            // 300000
#define PRE_TOT (V_W2 + V_XB + V_W1 + V_R1 + V_R2 + V_HIST)   // 663648

__global__ __launch_bounds__(256) void pre1_k(
    const int* __restrict__ dst, const int* __restrict__ et,
    const float* __restrict__ x, const float* __restrict__ W1,
    const float* __restrict__ root1, const float* __restrict__ W2,
    const float* __restrict__ root2,
    int* __restrict__ hist,
    unsigned short* __restrict__ xb, unsigned short* __restrict__ w1t,
    unsigned short* __restrict__ r1t, unsigned short* __restrict__ w2t,
    unsigned short* __restrict__ r2t) {
    int it = blockIdx.x * 256 + threadIdx.x;
    if (it < V_W2) {
        const int i = it * 4;                 // [r][k][n0..n0+3]
        int r = i >> 14, k = (i >> 7) & 127, n0 = i & 127;
        int kb = r * 4 + (k >> 5), q = (k >> 3) & 3, j = k & 7;
        int ct8 = n0 >> 4;                    // 4-aligned n0 never crosses ct8
        float4 wv = *(const float4*)(W2 + i);
        unsigned short* wp = w2t + (size_t)kb * 4096 + ct8 * 512
                             + (n0 & 15) * 32 + q * 8 + j;
        wp[0]  = f2b(wv.x); wp[32] = f2b(wv.y);
        wp[64] = f2b(wv.z); wp[96] = f2b(wv.w);
        return;
    }
    it -= V_W2;
    if (it < V_XB) {                          // contiguous bf16 copy of x
        const int i = it * 4;
        float4 xv = *(const float4*)(x + i);
        us4v v; v[0] = f2b(xv.x); v[1] = f2b(xv.y);
        v[2] = f2b(xv.z); v[3] = f2b(xv.w);
        *(us4v*)(xb + i) = v;
        return;
    }
    it -= V_XB;
    if (it < V_W1) {
        const int i = it * 4;                 // [rel][kk][n0..n0+3]
        int rel = i >> 11, kk = (i >> 7) & 15, n0 = i & 127;
        int kb = rel >> 1, k = ((rel & 1) << 4) + kk;
        int q = k >> 3, j = k & 7, ct8 = n0 >> 4;
        float4 wv = *(const float4*)(W1 + i);
        unsigned short* wp = w1t + kb * 4096 + ct8 * 512
                             + (n0 & 15) * 32 + q * 8 + j;
        wp[0]  = f2b(wv.x); wp[32] = f2b(wv.y);
        wp[64] = f2b(wv.z); wp[96] = f2b(wv.w);
        return;
    }
    it -= V_W1;
    if (it < V_R1) {
        const int i = it * 4;                 // root1 padded to K=32
        int k = i >> 7, n0 = i & 127;
        int q = k >> 3, j = k & 7, ct8 = n0 >> 4;
        float4 rv = (k < EMB) ? *(const float4*)(root1 + k * 128 + n0)
                              : float4{0.f, 0.f, 0.f, 0.f};
        unsigned short* wp = r1t + ct8 * 512 + (n0 & 15) * 32 + q * 8 + j;
        wp[0]  = f2b(rv.x); wp[32] = f2b(rv.y);
        wp[64] = f2b(rv.z); wp[96] = f2b(rv.w);
        return;
    }
    it -= V_R1;
    if (it < V_R2) {
        const int i = it * 4;                 // root2: [ks][ct8][512]
        int k = i >> 7, n0 = i & 127;
        int ks = k >> 5, q = (k >> 3) & 3, j = k & 7, ct8 = n0 >> 4;
        float4 rv = *(const float4*)(root2 + i);
        unsigned short* wp = r2t + (ks * 8 + ct8) * 512
                             + (n0 & 15) * 32 + q * 8 + j;
        wp[0]  = f2b(rv.x); wp[32] = f2b(rv.y);
        wp[64] = f2b(rv.z); wp[96] = f2b(rv.w);
        return;
    }
    it -= V_R2;
    if (it < V_HIST) {                        // 2 edges per thread
        const int e = it * 2;
        int2 d2 = *(const int2*)(dst + e);
        int2 t2 = *(const int2*)(et + e);
        atomicAdd(&hist[d2.x * N_REL + t2.x], 1);
        atomicAdd(&hist[d2.y * N_REL + t2.y], 1);
    }
}

// ======== 2-level scan over NB = 625 x 1024 chunks (+ inv fused) ========
__global__ void scan1_k(const int* __restrict__ hist, int* __restrict__ binoff,
                        int* __restrict__ cursors,
                        int* __restrict__ bsum, float* __restrict__ inv) {
    __shared__ int sh[256];
    const int t = threadIdx.x;
    const int base = blockIdx.x * 1024 + t * 4;
    int4 h4 = *(const int4*)(hist + base);
    float4 iv4;
    iv4.x = h4.x > 0 ? 1.0f / h4.x : 0.0f;
    iv4.y = h4.y > 0 ? 1.0f / h4.y : 0.0f;
    iv4.z = h4.z > 0 ? 1.0f / h4.z : 0.0f;
    iv4.w = h4.w > 0 ? 1.0f / h4.w : 0.0f;
    *(float4*)(inv + base) = iv4;
    int ts = h4.x + h4.y + h4.z + h4.w;
    sh[t] = ts;
    __syncthreads();
    for (int o = 1; o < 256; o <<= 1) {
        int v = (t >= o) ? sh[t - o] : 0;
        __syncthreads();
        sh[t] += v;
        __syncthreads();
    }
    int exc = sh[t] - ts;
    int4 b4;
    b4.x = exc;
    b4.y = exc + h4.x;
    b4.z = exc + h4.x + h4.y;
    b4.w = exc + h4.x + h4.y + h4.z;
    *(int4*)(binoff + base) = b4;
    *(int4*)(cursors + base) = b4;
    if (t == 255) bsum[blockIdx.x] = sh[255];
}

__global__ void scan2_k(const int* __restrict__ bsum, int* __restrict__ bbase,
                        int* __restrict__ binoff) {
    __shared__ int sh[1024];
    const int t = threadIdx.x;
    int v = (t < 625) ? bsum[t] : 0;
    sh[t] = v;
    __syncthreads();
    for (int o = 1; o < 1024; o <<= 1) {
        int u = (t >= o) ? sh[t - o] : 0;
        __syncthreads();
        sh[t] += u;
        __syncthreads();
    }
    if (t < 625) bbase[t] = sh[t] - v;
    if (t == 625) bbase[625] = N_EDGES;   // sentinel: chunk after the last
    if (t == 626) binoff[NB] = 0;         // local offset of sentinel bin
}

__global__ void scatter_k(const int* __restrict__ src, const int* __restrict__ dst,
                          const int* __restrict__ et, int* __restrict__ cursors,
                          const int* __restrict__ bbase, int* __restrict__ ssrc) {
    int it = blockIdx.x * 256 + threadIdx.x;
    if (it < 4) ssrc[N_EDGES + it] = 0;   // pad: safe src for speculative loads
    if (it < N_EDGES / 2) {
        const int e = it * 2;             // 2 edges per thread
        int2 s2 = *(const int2*)(src + e);
        int2 d2 = *(const int2*)(dst + e);
        int2 t2 = *(const int2*)(et + e);
        int b0 = d2.x * N_REL + t2.x;
        int p0 = atomicAdd(&cursors[b0], 1) + bbase[b0 >> 10];
        ssrc[p0] = s2.x;
        int b1 = d2.y * N_REL + t2.y;
        int p1 = atomicAdd(&cursors[b1], 1) + bbase[b1 >> 10];
        ssrc[p1] = s2.y;
    }
}

// ======== layer 1: barrier-phase gemm (unchanged, proven) ========
template<int ROWS, int ROWG, int NRC, int NIT, int KR>
__device__ __forceinline__ void gemm_body(
    const int* __restrict__ binoff, const int* __restrict__ bbase,
    const float* __restrict__ inv, const int* __restrict__ ssrc,
    const unsigned short* __restrict__ G,
    const unsigned short* __restrict__ Bw,
    const unsigned short* __restrict__ Br,
    unsigned short* __restrict__ fout, const float* __restrict__ bias) {

    constexpr int RG  = NRC * NIT;
    constexpr int KT  = (NRC * ROWG) / 32;
    constexpr int NCH = 256 / (ROWS * NRC);
    constexpr int CW  = ROWG / NCH;
    constexpr int CP8 = CW / 8;
    constexpr int LSS = NRC * ROWG + 8;
    constexpr int RT  = ROWS / 16;
    static_assert(NCH * CW == ROWG, "chunk covering");
    static_assert(CP8 * 8 == CW, "16B unit covering");
    static_assert(ROWS * NRC * NCH == 256, "all threads gather");
    static_assert(RG == 32, "single group");

    __shared__ __align__(16) unsigned short As[2][ROWS * LSS];
    __shared__ int   smO[ROWS * (RG + 1)];
    __shared__ float smI[ROWS * RG];

    const int t = threadIdx.x;
    const int w = t >> 6, lane = t & 63;
    const int q = lane >> 4, m16 = lane & 15;
    const int d0 = blockIdx.x * ROWS;
    const int colb = w * 32;
    const int cb16 = colb >> 4;
    const int fo = m16 * 32 + q * 8;
    const int brow = t / (NRC * NCH);
    const int rsub = (t / NCH) % NRC;
    const int gcc  = t % NCH;
    const int mb  = brow * (RG + 1) + rsub;
    const int mbI = brow * RG + rsub;
    int uo[CP8];
#pragma unroll
    for (int j = 0; j < CP8; ++j) uo[j] = (gcc + j * NCH) * 8;
    const int lbase = brow * LSS + rsub * ROWG;

    for (int i = t; i < ROWS * (RG + 1); i += 256) {
        int row = i / (RG + 1), rr = i % (RG + 1);
        int bi = (d0 + row) * N_REL + rr;
        smO[i] = binoff[bi] + bbase[bi >> 10];
    }
    for (int i = t; i < ROWS * RG; i += 256) {
        int row = i / RG, rr = i % RG;
        smI[i] = inv[(d0 + row) * N_REL + rr];
    }
    lds_barrier();

    f4v acc[RT][2];
#pragma unroll
    for (int rt = 0; rt < RT; ++rt)
#pragma unroll
        for (int ct = 0; ct < 2; ++ct) acc[rt][ct] = f4v{0.f, 0.f, 0.f, 0.f};

    us8v gE[4][CP8];
#pragma unroll
    for (int e = 0; e < 4; ++e)
#pragma unroll
        for (int j = 0; j < CP8; ++j) gE[e][j] = us8v{};
    int sx[4] = {0, 0, 0, 0};

    {
        const int so = smO[mb], cnt = smO[mb + 1] - so;
        int s0 = ssrc[so], s1 = ssrc[so + 1], s2 = ssrc[so + 2], s3 = ssrc[so + 3];
        if (cnt >= 1) {
            const unsigned short* gp = G + (size_t)s0 * ROWG;
#pragma unroll
            for (int j = 0; j < CP8; ++j) gE[0][j] = *(const us8v*)(gp + uo[j]);
        }
        if (cnt >= 2) {
            const unsigned short* gp = G + (size_t)s1 * ROWG;
#pragma unroll
            for (int j = 0; j < CP8; ++j) gE[1][j] = *(const us8v*)(gp + uo[j]);
        }
        if (cnt >= 3) {
            const unsigned short* gp = G + (size_t)s2 * ROWG;
#pragma unroll
            for (int j = 0; j < CP8; ++j) gE[2][j] = *(const us8v*)(gp + uo[j]);
        }
        if (cnt >= 4) {
            const unsigned short* gp = G + (size_t)s3 * ROWG;
#pragma unroll
            for (int j = 0; j < CP8; ++j) gE[3][j] = *(const us8v*)(gp + uo[j]);
        }
        if (NIT > 1) {
            const int so1 = smO[mb + NRC];
            sx[0] = ssrc[so1]; sx[1] = ssrc[so1 + 1];
            sx[2] = ssrc[so1 + 2]; sx[3] = ssrc[so1 + 3];
        }
    }

    bf8v bfr[2][KT];
#pragma unroll
    for (int ct = 0; ct < 2; ++ct)
#pragma unroll
        for (int ks = 0; ks < KT; ++ks)
            bfr[ct][ks] = *(const bf8v*)(Bw + ((size_t)ks * 8 + cb16 + ct) * 512 + fo);

#pragma unroll 2
    for (int it = 0; it < NIT; ++it) {
        unsigned short* Ab = As[it & 1];
        {
            const int so = smO[mb + it * NRC], eo = smO[mb + it * NRC + 1];
            const int cnt = eo - so;
            const float m2 = cnt >= 2 ? 1.f : 0.f;
            const float m3 = cnt >= 3 ? 1.f : 0.f;
            const float m4 = cnt >= 4 ? 1.f : 0.f;
            float a[CW];
#pragma unroll
            for (int j = 0; j < CP8; ++j)
#pragma unroll
                for (int k = 0; k < 8; ++k)
                    a[j * 8 + k] = b2f(gE[0][j][k]) + m2 * b2f(gE[1][j][k])
                                 + m3 * b2f(gE[2][j][k]) + m4 * b2f(gE[3][j][k]);
            for (int p = so + 4; p < eo; ++p) {
                const unsigned short* gp = G + (size_t)ssrc[p] * ROWG;
#pragma unroll
                for (int j = 0; j < CP8; ++j) {
                    us8v g = *(const us8v*)(gp + uo[j]);
#pragma unroll
                    for (int k = 0; k < 8; ++k) a[j * 8 + k] += b2f(g[k]);
                }
            }
            const float iv = smI[mbI + it * NRC];
            unsigned short* wp = &Ab[lbase];
#pragma unroll
            for (int j = 0; j < CP8; ++j) {
                us8v sv;
#pragma unroll
                for (int k = 0; k < 8; ++k) sv[k] = f2b(a[j * 8 + k] * iv);
                *(us8v*)(wp + uo[j]) = sv;
            }

            if (it + 1 < NIT) {
                const int b1o = mb + (it + 1) * NRC;
                const int c1 = smO[b1o + 1] - smO[b1o];
                if (c1 >= 1) {
                    const unsigned short* gp = G + (size_t)sx[0] * ROWG;
#pragma unroll
                    for (int j = 0; j < CP8; ++j) gE[0][j] = *(const us8v*)(gp + uo[j]);
                }
                if (c1 >= 2) {
                    const unsigned short* gp = G + (size_t)sx[1] * ROWG;
#pragma unroll
                    for (int j = 0; j < CP8; ++j) gE[1][j] = *(const us8v*)(gp + uo[j]);
                }
                if (c1 >= 3) {
                    const unsigned short* gp = G + (size_t)sx[2] * ROWG;
#pragma unroll
                    for (int j = 0; j < CP8; ++j) gE[2][j] = *(const us8v*)(gp + uo[j]);
                }
                if (c1 >= 4) {
                    const unsigned short* gp = G + (size_t)sx[3] * ROWG;
#pragma unroll
                    for (int j = 0; j < CP8; ++j) gE[3][j] = *(const us8v*)(gp + uo[j]);
                }
                if (it + 2 < NIT) {
                    const int so2 = smO[mb + (it + 2) * NRC];
                    sx[0] = ssrc[so2]; sx[1] = ssrc[so2 + 1];
                    sx[2] = ssrc[so2 + 2]; sx[3] = ssrc[so2 + 3];
                }
            }
        }
        lds_barrier();

        __builtin_amdgcn_s_setprio(1);
#pragma unroll
        for (int rt = 0; rt < RT; ++rt) {
            const unsigned short* ar = &Ab[(m16 + 16 * rt) * LSS];
#pragma unroll
            for (int ks = 0; ks < KT; ++ks) {
                bf8v af = *(const bf8v*)(ar + ks * 32 + q * 8);
                acc[rt][0] = __builtin_amdgcn_mfma_f32_16x16x32_bf16(af, bfr[0][ks], acc[rt][0], 0, 0, 0);
                acc[rt][1] = __builtin_amdgcn_mfma_f32_16x16x32_bf16(af, bfr[1][ks], acc[rt][1], 0, 0, 0);
            }
        }
        __builtin_amdgcn_s_setprio(0);

        if (it + 1 < NIT) {
            const int kb0 = ((it + 1) * NRC * ROWG) >> 5;
#pragma unroll
            for (int ct = 0; ct < 2; ++ct)
#pragma unroll
                for (int ks = 0; ks < KT; ++ks)
                    bfr[ct][ks] = *(const bf8v*)(Bw + ((size_t)(kb0 + ks) * 8 + cb16 + ct) * 512 + fo);
        } else {
#pragma unroll
            for (int ct = 0; ct < 2; ++ct)
#pragma unroll
                for (int ks = 0; ks < KR; ++ks)
                    bfr[ct][ks] = *(const bf8v*)(Br + ((size_t)ks * 8 + cb16 + ct) * 512 + fo);
        }
    }

    {
#pragma unroll
        for (int rt = 0; rt < RT; ++rt) {
            const unsigned short* gr = G + (size_t)(d0 + m16 + 16 * rt) * ROWG;
#pragma unroll
            for (int ks = 0; ks < KR; ++ks) {
                bf8v af = bf8v{0, 0, 0, 0, 0, 0, 0, 0};
                if (ks * 32 + q * 8 + 8 <= ROWG)
                    af = *(const bf8v*)(gr + ks * 32 + q * 8);
                acc[rt][0] = __builtin_amdgcn_mfma_f32_16x16x32_bf16(af, bfr[0][ks], acc[rt][0], 0, 0, 0);
                acc[rt][1] = __builtin_amdgcn_mfma_f32_16x16x32_bf16(af, bfr[1][ks], acc[rt][1], 0, 0, 0);
            }
        }
    }

#pragma unroll
    for (int ct = 0; ct < 2; ++ct) {
        const int col = colb + 16 * ct + m16;
        const float bb = bias[col];
#pragma unroll
        for (int rt = 0; rt < RT; ++rt) {
#pragma unroll
            for (int g = 0; g < 4; ++g) {
                const int rr = 16 * rt + q * 4 + g;
                fout[(size_t)(d0 + rr) * HID + col] =
                    f2b(fmaxf(acc[rt][ct][g] + bb, 0.0f));
            }
        }
    }
}

__global__ __launch_bounds__(256) void gemm_l1(
    const int* __restrict__ binoff, const int* __restrict__ bbase,
    const float* __restrict__ inv, const int* __restrict__ ssrc,
    const unsigned short* __restrict__ G, const unsigned short* __restrict__ Bw,
    const unsigned short* __restrict__ Br,
    unsigned short* __restrict__ fout, const float* __restrict__ bias) {
    gemm_body<32, 16, 4, 8, 1>(binoff, bbase, inv, ssrc, G, Bw, Br, fout, bias);
}

// ======== layer 2: WAVE-AUTONOMOUS, zero-barrier ========
// 128-thread blocks = 2 independent waves; each wave owns 16 rows end-to-end:
// private meta, private double-buffered LDS tile (producer == consumer wave, so
// RAW ordering is in-wave DS order -> NO s_barrier in the whole kernel).
// Waves drift to different relations; gather-VALU, TA and MFMA pipes overlap
// across the ~12 resident waves/CU instead of bursting in lockstep.
__global__ __launch_bounds__(128) void gemm_l2w(
    const int* __restrict__ binoff, const int* __restrict__ bbase,
    const float* __restrict__ inv, const int* __restrict__ ssrc,
    const unsigned short* __restrict__ G,    // h1b rows [N, 128]
    const unsigned short* __restrict__ Bw,   // w2t [kb=r*4+ks][ct8][512]
    const unsigned short* __restrict__ Br,   // r2t [ks][ct8][512]
    float* __restrict__ outf, const float* __restrict__ bias) {

    constexpr int LSS = 136;                 // 128 + 8 pad (2-way bank alias: free)
    __shared__ __align__(16) unsigned short As[2][2][16 * LSS]; // [wave][buf]
    __shared__ int   smO[2][16 * 33];
    __shared__ float smI[2][16 * 32];

    const int lane = threadIdx.x & 63;
    const int wv   = threadIdx.x >> 6;
    const int q = lane >> 4, m16 = lane & 15;
    const int d0 = blockIdx.x * 32 + wv * 16;     // this wave's 16 rows
    const int fo = m16 * 32 + q * 8;              // B-fragment lane offset
    const int brow = lane >> 2;                   // gather row 0..15 (4 lanes/row)
    const int gcc  = lane & 3;
    const int mb   = brow * 33;
    int uo[4];
#pragma unroll
    for (int j = 0; j < 4; ++j) uo[j] = (gcc + j * 4) * 8;  // unit-interleaved
    const int lbase = brow * LSS;

    // ---- wave-private meta preload (no cross-wave deps -> no barrier) ----
    for (int i = lane; i < 16 * 33; i += 64) {
        int row = i / 33, rr = i % 33;
        int bi = (d0 + row) * N_REL + rr;
        smO[wv][i] = binoff[bi] + bbase[bi >> 10];
    }
    for (int i = lane; i < 16 * 32; i += 64) {
        smI[wv][i] = inv[(d0 + (i >> 5)) * N_REL + (i & 31)];
    }

    f4v acc[8];
#pragma unroll
    for (int ct = 0; ct < 8; ++ct) acc[ct] = f4v{0.f, 0.f, 0.f, 0.f};

    // ---- staged-edge pipeline (1-deep, 4 staged edges, CP8=4) ----
    us8v gE[4][4];
#pragma unroll
    for (int e = 0; e < 4; ++e)
#pragma unroll
        for (int j = 0; j < 4; ++j) gE[e][j] = us8v{};
    int sx[4] = {0, 0, 0, 0};

    auto stage4 = [&](int s0, int s1, int s2, int s3, int c) __attribute__((always_inline)) {
        if (c >= 1) {
            const unsigned short* gp = G + (size_t)s0 * HID;
#pragma unroll
            for (int j = 0; j < 4; ++j) gE[0][j] = *(const us8v*)(gp + uo[j]);
        }
        if (c >= 2) {
            const unsigned short* gp = G + (size_t)s1 * HID;
#pragma unroll
            for (int j = 0; j < 4; ++j) gE[1][j] = *(const us8v*)(gp + uo[j]);
        }
        if (c >= 3) {
            const unsigned short* gp = G + (size_t)s2 * HID;
#pragma unroll
            for (int j = 0; j < 4; ++j) gE[2][j] = *(const us8v*)(gp + uo[j]);
        }
        if (c >= 4) {
            const unsigned short* gp = G + (size_t)s3 * HID;
#pragma unroll
            for (int j = 0; j < 4; ++j) gE[3][j] = *(const us8v*)(gp + uo[j]);
        }
    };

    // prologue: stage rel=0; sx = srcs(rel=1)
    {
        const int so = smO[wv][mb], cnt = smO[wv][mb + 1] - so;
        stage4(ssrc[so], ssrc[so + 1], ssrc[so + 2], ssrc[so + 3], cnt);
        const int so1 = smO[wv][mb + 1];
        sx[0] = ssrc[so1]; sx[1] = ssrc[so1 + 1];
        sx[2] = ssrc[so1 + 2]; sx[3] = ssrc[so1 + 3];
    }

    for (int rel = 0; rel < N_REL; ++rel) {
        unsigned short* Ab = &As[wv][rel & 1][0];
        // ---- gather: combine 4 staged edges per-j (fused scale+bf16) ----
        {
            const int so = smO[wv][mb + rel], eo = smO[wv][mb + rel + 1];
            const int cnt = eo - so;
            const float m2 = cnt >= 2 ? 1.f : 0.f;
            const float m3 = cnt >= 3 ? 1.f : 0.f;
            const float m4 = cnt >= 4 ? 1.f : 0.f;
            const float iv = smI[wv][brow * 32 + rel];
            unsigned short* wp = &Ab[lbase];
#pragma unroll
            for (int j = 0; j < 4; ++j) {
                float aj[8];
#pragma unroll
                for (int k = 0; k < 8; ++k)
                    aj[k] = b2f(gE[0][j][k]) + m2 * b2f(gE[1][j][k])
                          + m3 * b2f(gE[2][j][k]) + m4 * b2f(gE[3][j][k]);
                for (int p = so + 4; p < eo; ++p) {   // rare tail
                    const unsigned short* gp = G + (size_t)ssrc[p] * HID;
                    us8v g = *(const us8v*)(gp + uo[j]);
#pragma unroll
                    for (int k = 0; k < 8; ++k) aj[k] += b2f(g[k]);
                }
                us8v sv;
#pragma unroll
                for (int k = 0; k < 8; ++k) sv[k] = f2b(aj[k] * iv);
                *(us8v*)(wp + uo[j]) = sv;
            }

            // re-stage rel+1's edges; refill sx for rel+2
            if (rel + 1 < N_REL) {
                const int b1o = mb + rel + 1;
                stage4(sx[0], sx[1], sx[2], sx[3], smO[wv][b1o + 1] - smO[wv][b1o]);
                if (rel + 2 < N_REL) {
                    const int so2 = smO[wv][mb + rel + 2];
                    sx[0] = ssrc[so2]; sx[1] = ssrc[so2 + 1];
                    sx[2] = ssrc[so2 + 2]; sx[3] = ssrc[so2 + 3];
                }
            }
        }

        // ---- A fragments (own LDS; in-wave DS order, no barrier) ----
        bf8v af[4];
        {
            const unsigned short* ar = &Ab[m16 * LSS + q * 8];
#pragma unroll
            for (int ks = 0; ks < 4; ++ks)
                af[ks] = *(const bf8v*)(ar + ks * 32);
        }

        // ---- B + MFMA: 8 col-tiles x 4 K-steps, 2-buffer B rotation ----
        const unsigned short* Bp = Bw + (size_t)rel * 16384;
        bf8v b0[4], b1[4];
#pragma unroll
        for (int ks = 0; ks < 4; ++ks)
            b0[ks] = *(const bf8v*)(Bp + ((size_t)ks * 8 + 0) * 512 + fo);
        __builtin_amdgcn_s_setprio(1);
#pragma unroll
        for (int ct = 0; ct < 8; ct += 2) {
#pragma unroll
            for (int ks = 0; ks < 4; ++ks)
                b1[ks] = *(const bf8v*)(Bp + ((size_t)ks * 8 + ct + 1) * 512 + fo);
#pragma unroll
            for (int ks = 0; ks < 4; ++ks)
                acc[ct] = __builtin_amdgcn_mfma_f32_16x16x32_bf16(af[ks], b0[ks], acc[ct], 0, 0, 0);
            if (ct + 2 < 8) {
#pragma unroll
                for (int ks = 0; ks < 4; ++ks)
                    b0[ks] = *(const bf8v*)(Bp + ((size_t)ks * 8 + ct + 2) * 512 + fo);
            }
#pragma unroll
            for (int ks = 0; ks < 4; ++ks)
                acc[ct + 1] = __builtin_amdgcn_mfma_f32_16x16x32_bf16(af[ks], b1[ks], acc[ct + 1], 0, 0, 0);
        }
        __builtin_amdgcn_s_setprio(0);
    }

    // ---- root transform: A straight from global ----
    {
        const unsigned short* gr = G + (size_t)(d0 + m16) * HID + q * 8;
        bf8v af[4];
#pragma unroll
        for (int ks = 0; ks < 4; ++ks)
            af[ks] = *(const bf8v*)(gr + ks * 32);
        bf8v b0[4];
#pragma unroll
        for (int ct = 0; ct < 8; ++ct) {
#pragma unroll
            for (int ks = 0; ks < 4; ++ks)
                b0[ks] = *(const bf8v*)(Br + ((size_t)ks * 8 + ct) * 512 + fo);
#pragma unroll
            for (int ks = 0; ks < 4; ++ks)
                acc[ct] = __builtin_amdgcn_mfma_f32_16x16x32_bf16(af[ks], b0[ks], acc[ct], 0, 0, 0);
        }
    }

    // ---- epilogue: bias + fp32 -> out ----
#pragma unroll
    for (int ct = 0; ct < 8; ++ct) {
        const int col = ct * 16 + m16;
        const float bb = bias[col];
#pragma unroll
        for (int g = 0; g < 4; ++g) {
            const int rr = q * 4 + g;
            outf[(size_t)(d0 + rr) * HID + col] = acc[ct][g] + bb;
        }
    }
}

extern "C" void kernel_launch(void* const* d_in, const int* in_sizes, int n_in,
                              void* d_out, int out_size, void* d_ws, size_t ws_size,
                              hipStream_t stream) {
    const int*   ei    = (const int*)d_in[0];   // [2, E]
    const int*   et    = (const int*)d_in[1];   // [E]
    const float* x     = (const float*)d_in[2]; // [N, 16]
    const float* W1    = (const float*)d_in[3]; // [32, 16, 128]
    const float* root1 = (const float*)d_in[4]; // [16, 128]
    const float* b1    = (const float*)d_in[5]; // [128]
    const float* W2    = (const float*)d_in[6]; // [32, 128, 128]
    const float* root2 = (const float*)d_in[7]; // [128, 128]
    const float* b2    = (const float*)d_in[8]; // [128]
    float* out = (float*)d_out;

    // ---- workspace layout (~16 MB) ----
    char* ws = (char*)d_ws;
    size_t off = 0;
    auto alloc = [&](size_t bytes) { void* p = ws + off; off = (off + bytes + 63) & ~(size_t)63; return p; };
    int*   hist    = (int*)  alloc((size_t)NB * 4);
    int*   binoff  = (int*)  alloc((size_t)(NB + 1) * 4);
    int*   cursors = (int*)  alloc((size_t)NB * 4);
    float* inv     = (float*)alloc((size_t)NB * 4);
    int*   bsum    = (int*)  alloc(625 * 4);
    int*   bbase   = (int*)  alloc(626 * 4);
    int*   ssrc    = (int*)  alloc((size_t)(N_EDGES + 4) * 4);
    unsigned short* xb  = (unsigned short*)alloc((size_t)N_NODES * EMB * 2);
    unsigned short* h1b = (unsigned short*)alloc((size_t)N_NODES * HID * 2);
    unsigned short* w1t = (unsigned short*)alloc((size_t)N_REL * EMB * HID * 2);
    unsigned short* r1t = (unsigned short*)alloc((size_t)HID * 32 * 2);
    unsigned short* w2t = (unsigned short*)alloc((size_t)N_REL * HID * HID * 2);
    unsigned short* r2t = (unsigned short*)alloc((size_t)HID * HID * 2);

    const int* src = ei;
    const int* dst = ei + N_EDGES;

    hipMemsetAsync(hist, 0, (size_t)NB * 4, stream);
    pre1_k<<<(PRE_TOT + 255) / 256, 256, 0, stream>>>(
        dst, et, x, W1, root1, W2, root2, hist, xb, w1t, r1t, w2t, r2t);
    scan1_k<<<NB / 1024, 256, 0, stream>>>(hist, binoff, cursors, bsum, inv);
    scan2_k<<<1, 1024, 0, stream>>>(bsum, bbase, binoff);
    scatter_k<<<(N_EDGES / 2 + 255) / 256, 256, 0, stream>>>(src, dst, et, cursors, bbase, ssrc);

    // ---- layer 1: barrier-phase gemm (unchanged) ----
    gemm_l1<<<dim3(625, 1), 256, 0, stream>>>(
        binoff, bbase, inv, ssrc, xb, w1t, r1t, h1b, b1);

    // ---- layer 2: wave-autonomous, zero-barrier; 625 x 128-thread blocks ----
    gemm_l2w<<<dim3(625, 1), 128, 0, stream>>>(
        binoff, bbase, inv, ssrc, h1b, w2t, r2t, out, b2);
}

// Round 12
// 227.220 us; speedup vs baseline: 1.3796x; 1.3796x over previous
//
#include <hip/hip_runtime.h>
#include <hip/hip_bf16.h>

#define N_NODES 20000
#define N_REL 32
#define HID 128
#define EMB 16
#define N_EDGES 600000
#define NB (N_NODES * N_REL)   // 640000 bins

typedef __attribute__((ext_vector_type(8))) short  bf8v;   // 8 bf16 (MFMA A/B frag)
typedef __attribute__((ext_vector_type(8))) unsigned short us8v; // 16-byte unit
typedef __attribute__((ext_vector_type(4))) unsigned short us4v; // 8-byte unit
typedef __attribute__((ext_vector_type(4))) unsigned int   ui4v; // 16B as 4 u32
typedef __attribute__((ext_vector_type(4))) float  f4v;    // MFMA C/D frag
typedef __attribute__((ext_vector_type(2))) float  f2v;    // packed-pair fp32

__device__ __forceinline__ unsigned short f2b(float f) {
    __hip_bfloat16 h = __float2bfloat16(f);
    return __builtin_bit_cast(unsigned short, h);
}
__device__ __forceinline__ float b2f(unsigned short u) {
    unsigned int x = ((unsigned int)u) << 16;
    return __builtin_bit_cast(float, x);
}
// unpack a u32 holding two bf16 into {lo, hi} floats (1 op each)
__device__ __forceinline__ f2v up2(unsigned int w) {
    f2v r;
    r[0] = __builtin_bit_cast(float, w << 16);
    r[1] = __builtin_bit_cast(float, w & 0xFFFF0000u);
    return r;
}

// Barrier with LDS-only drain (global prefetches stay in flight).
__device__ __forceinline__ void lds_barrier() {
    asm volatile("s_waitcnt lgkmcnt(0)\n\ts_barrier" ::: "memory");
}

// ======== pre-pass (VECTORIZED): histogram + fragment-major bf16 layouts ====
// Unified B layout [kb][ct8][512] where kb is a global K-block (32 k's).
//  - W2: kb = r*4 + ks                      (256 kb)
//  - W1: kb packs TWO relations per K-block (k<16 -> rel 2kb, k>=16 -> rel 2kb+1)
//  - xb: raw bf16 copy of x, 16 shorts/row (no zero pad).
#define V_W2  (N_REL * HID * HID / 4)   // 262144
#define V_XB  (N_NODES * EMB / 4)       // 80000
#define V_W1  (N_REL * EMB * HID / 4)   // 16384
#define V_R1  (HID * 32 / 4)            // 1024
#define V_R2  (HID * HID / 4)           // 4096
#define V_HIST (N_EDGES / 2)            // 300000
#define PRE_TOT (V_W2 + V_XB + V_W1 + V_R1 + V_R2 + V_HIST)   // 663648

__global__ __launch_bounds__(256) void pre1_k(
    const int* __restrict__ dst, const int* __restrict__ et,
    const float* __restrict__ x, const float* __restrict__ W1,
    const float* __restrict__ root1, const float* __restrict__ W2,
    const float* __restrict__ root2,
    int* __restrict__ hist,
    unsigned short* __restrict__ xb, unsigned short* __restrict__ w1t,
    unsigned short* __restrict__ r1t, unsigned short* __restrict__ w2t,
    unsigned short* __restrict__ r2t) {
    int it = blockIdx.x * 256 + threadIdx.x;
    if (it < V_W2) {
        const int i = it * 4;                 // [r][k][n0..n0+3]
        int r = i >> 14, k = (i >> 7) & 127, n0 = i & 127;
        int kb = r * 4 + (k >> 5), q = (k >> 3) & 3, j = k & 7;
        int ct8 = n0 >> 4;                    // 4-aligned n0 never crosses ct8
        float4 wv = *(const float4*)(W2 + i);
        unsigned short* wp = w2t + (size_t)kb * 4096 + ct8 * 512
                             + (n0 & 15) * 32 + q * 8 + j;
        wp[0]  = f2b(wv.x); wp[32] = f2b(wv.y);
        wp[64] = f2b(wv.z); wp[96] = f2b(wv.w);
        return;
    }
    it -= V_W2;
    if (it < V_XB) {                          // contiguous bf16 copy of x
        const int i = it * 4;
        float4 xv = *(const float4*)(x + i);
        us4v v; v[0] = f2b(xv.x); v[1] = f2b(xv.y);
        v[2] = f2b(xv.z); v[3] = f2b(xv.w);
        *(us4v*)(xb + i) = v;
        return;
    }
    it -= V_XB;
    if (it < V_W1) {
        const int i = it * 4;                 // [rel][kk][n0..n0+3]
        int rel = i >> 11, kk = (i >> 7) & 15, n0 = i & 127;
        int kb = rel >> 1, k = ((rel & 1) << 4) + kk;
        int q = k >> 3, j = k & 7, ct8 = n0 >> 4;
        float4 wv = *(const float4*)(W1 + i);
        unsigned short* wp = w1t + kb * 4096 + ct8 * 512
                             + (n0 & 15) * 32 + q * 8 + j;
        wp[0]  = f2b(wv.x); wp[32] = f2b(wv.y);
        wp[64] = f2b(wv.z); wp[96] = f2b(wv.w);
        return;
    }
    it -= V_W1;
    if (it < V_R1) {
        const int i = it * 4;                 // root1 padded to K=32
        int k = i >> 7, n0 = i & 127;
        int q = k >> 3, j = k & 7, ct8 = n0 >> 4;
        float4 rv = (k < EMB) ? *(const float4*)(root1 + k * 128 + n0)
                              : float4{0.f, 0.f, 0.f, 0.f};
        unsigned short* wp = r1t + ct8 * 512 + (n0 & 15) * 32 + q * 8 + j;
        wp[0]  = f2b(rv.x); wp[32] = f2b(rv.y);
        wp[64] = f2b(rv.z); wp[96] = f2b(rv.w);
        return;
    }
    it -= V_R1;
    if (it < V_R2) {
        const int i = it * 4;                 // root2: [ks][ct8][512]
        int k = i >> 7, n0 = i & 127;
        int ks = k >> 5, q = (k >> 3) & 3, j = k & 7, ct8 = n0 >> 4;
        float4 rv = *(const float4*)(root2 + i);
        unsigned short* wp = r2t + (ks * 8 + ct8) * 512
                             + (n0 & 15) * 32 + q * 8 + j;
        wp[0]  = f2b(rv.x); wp[32] = f2b(rv.y);
        wp[64] = f2b(rv.z); wp[96] = f2b(rv.w);
        return;
    }
    it -= V_R2;
    if (it < V_HIST) {                        // 2 edges per thread
        const int e = it * 2;
        int2 d2 = *(const int2*)(dst + e);
        int2 t2 = *(const int2*)(et + e);
        atomicAdd(&hist[d2.x * N_REL + t2.x], 1);
        atomicAdd(&hist[d2.y * N_REL + t2.y], 1);
    }
}

// ======== 2-level scan over NB = 625 x 1024 chunks (+ inv fused) ========
__global__ void scan1_k(const int* __restrict__ hist, int* __restrict__ binoff,
                        int* __restrict__ cursors,
                        int* __restrict__ bsum, float* __restrict__ inv) {
    __shared__ int sh[256];
    const int t = threadIdx.x;
    const int base = blockIdx.x * 1024 + t * 4;
    int4 h4 = *(const int4*)(hist + base);
    float4 iv4;
    iv4.x = h4.x > 0 ? 1.0f / h4.x : 0.0f;
    iv4.y = h4.y > 0 ? 1.0f / h4.y : 0.0f;
    iv4.z = h4.z > 0 ? 1.0f / h4.z : 0.0f;
    iv4.w = h4.w > 0 ? 1.0f / h4.w : 0.0f;
    *(float4*)(inv + base) = iv4;
    int ts = h4.x + h4.y + h4.z + h4.w;
    sh[t] = ts;
    __syncthreads();
    for (int o = 1; o < 256; o <<= 1) {
        int v = (t >= o) ? sh[t - o] : 0;
        __syncthreads();
        sh[t] += v;
        __syncthreads();
    }
    int exc = sh[t] - ts;
    int4 b4;
    b4.x = exc;
    b4.y = exc + h4.x;
    b4.z = exc + h4.x + h4.y;
    b4.w = exc + h4.x + h4.y + h4.z;
    *(int4*)(binoff + base) = b4;
    *(int4*)(cursors + base) = b4;
    if (t == 255) bsum[blockIdx.x] = sh[255];
}

__global__ void scan2_k(const int* __restrict__ bsum, int* __restrict__ bbase,
                        int* __restrict__ binoff) {
    __shared__ int sh[1024];
    const int t = threadIdx.x;
    int v = (t < 625) ? bsum[t] : 0;
    sh[t] = v;
    __syncthreads();
    for (int o = 1; o < 1024; o <<= 1) {
        int u = (t >= o) ? sh[t - o] : 0;
        __syncthreads();
        sh[t] += u;
        __syncthreads();
    }
    if (t < 625) bbase[t] = sh[t] - v;
    if (t == 625) bbase[625] = N_EDGES;   // sentinel: chunk after the last
    if (t == 626) binoff[NB] = 0;         // local offset of sentinel bin
}

__global__ void scatter_k(const int* __restrict__ src, const int* __restrict__ dst,
                          const int* __restrict__ et, int* __restrict__ cursors,
                          const int* __restrict__ bbase, int* __restrict__ ssrc) {
    int it = blockIdx.x * 256 + threadIdx.x;
    if (it < 4) ssrc[N_EDGES + it] = 0;   // pad: safe src for speculative loads
    if (it < N_EDGES / 2) {
        const int e = it * 2;             // 2 edges per thread
        int2 s2 = *(const int2*)(src + e);
        int2 d2 = *(const int2*)(dst + e);
        int2 t2 = *(const int2*)(et + e);
        int b0 = d2.x * N_REL + t2.x;
        int p0 = atomicAdd(&cursors[b0], 1) + bbase[b0 >> 10];
        ssrc[p0] = s2.x;
        int b1 = d2.y * N_REL + t2.y;
        int p1 = atomicAdd(&cursors[b1], 1) + bbase[b1 >> 10];
        ssrc[p1] = s2.y;
    }
}

// ======== fused aggregate+transform (R10 structure; per-j packed gather) ====
// ROWS : node rows per block (32 -> 625 blocks: best measured geometry)
// ROWG : shorts per G row (16 for layer 1, 128 for layer 2)
// NRC  : relations concatenated into one K per iteration
// NIT  : iterations per block; RG = NRC*NIT = 32 relations (single group)
// KR   : K-blocks of the root transform
// OUT  : 1 = bias+ReLU+bf16 -> fout (layer 1); 2 = bias+fp32 -> outf (layer 2)
// R12: gather combine is per-j streaming on float2 ext-vectors (packed-pair
// unpack: 1 op / 2 elems; combine fmas eligible for v_pk_fma_f32). Bit-identical
// math (same IEEE adds/fmas, same RNE bf16 pack).
template<int ROWS, int ROWG, int NRC, int NIT, int KR, int OUT>
__device__ __forceinline__ void gemm_body(
    const int* __restrict__ binoff, const int* __restrict__ bbase,
    const float* __restrict__ inv, const int* __restrict__ ssrc,
    const unsigned short* __restrict__ G,    // bf16 rows [*, ROWG]
    const unsigned short* __restrict__ Bw,   // bf16 frag-major [kb][ct8][512]
    const unsigned short* __restrict__ Br,   // bf16 frag-major [ks][ct8][512]
    float* __restrict__ outf, unsigned short* __restrict__ fout,
    const float* __restrict__ bias) {

    constexpr int RG  = NRC * NIT;
    constexpr int KT  = (NRC * ROWG) / 32;      // MFMA K-steps per iteration
    constexpr int NCH = 256 / (ROWS * NRC);     // gather threads per (row,rel)
    constexpr int CW  = ROWG / NCH;             // shorts per gather thread
    constexpr int CP8 = CW / 8;                 // 16B units per gather thread
    constexpr int LSS = NRC * ROWG + 8;         // LDS row stride (shorts)
    constexpr int RT  = ROWS / 16;              // 16-row MFMA tiles per block
    static_assert(NCH * CW == ROWG, "chunk covering must be exact");
    static_assert(CP8 * 8 == CW, "16B unit covering");
    static_assert(KT * 32 == NRC * ROWG, "K must be a multiple of 32");
    static_assert(ROWS * NRC * NCH == 256, "all threads gather");
    static_assert(RG == 32, "single group covers all relations");
    static_assert(RT * 16 == ROWS, "rows multiple of 16");

    __shared__ __align__(16) unsigned short As[2][ROWS * LSS];
    __shared__ int   smO[ROWS * (RG + 1)];
    __shared__ float smI[ROWS * RG];

    const int t = threadIdx.x;
    const int w = t >> 6, lane = t & 63;
    const int q = lane >> 4, m16 = lane & 15;
    const int d0 = blockIdx.x * ROWS;
    const int colb = w * 32;
    const int cb16 = colb >> 4;                 // base coltile index
    const int fo = m16 * 32 + q * 8;            // lane offset within a 512-short fragment
    const int brow = t / (NRC * NCH);           // gather row 0..ROWS-1
    const int rsub = (t / NCH) % NRC;           // relation slice within iteration
    const int gcc  = t % NCH;                   // chunk within slice
    const int mb  = brow * (RG + 1) + rsub;
    const int mbI = brow * RG + rsub;
    // unit offsets (shorts) within this thread's (row,rel) slice
    int uo[CP8];
#pragma unroll
    for (int j = 0; j < CP8; ++j) uo[j] = (gcc + j * NCH) * 8;
    const int lbase = brow * LSS + rsub * ROWG; // LDS short offset of slice

    // ---- meta preload (all 32 relations of this node tile); bbase fused ----
    for (int i = t; i < ROWS * (RG + 1); i += 256) {
        int row = i / (RG + 1), rr = i % (RG + 1);
        int bi = (d0 + row) * N_REL + rr;
        smO[i] = binoff[bi] + bbase[bi >> 10];
    }
    for (int i = t; i < ROWS * RG; i += 256) {
        int row = i / RG, rr = i % RG;
        smI[i] = inv[(d0 + row) * N_REL + rr];
    }
    lds_barrier();

    f4v acc[RT][2];
#pragma unroll
    for (int rt = 0; rt < RT; ++rt)
#pragma unroll
        for (int ct = 0; ct < 2; ++ct) acc[rt][ct] = f4v{0.f, 0.f, 0.f, 0.f};

    // ---- staged-edge pipeline state (1-deep: best measured) ----
    us8v gE[4][CP8];
#pragma unroll
    for (int e = 0; e < 4; ++e)
#pragma unroll
        for (int j = 0; j < CP8; ++j) gE[e][j] = us8v{};
    int sx[4] = {0, 0, 0, 0};

    {
        const int so = smO[mb], cnt = smO[mb + 1] - so;
        int s0 = ssrc[so], s1 = ssrc[so + 1], s2 = ssrc[so + 2], s3 = ssrc[so + 3]; // pad-safe
        if (cnt >= 1) {
            const unsigned short* gp = G + (size_t)s0 * ROWG;
#pragma unroll
            for (int j = 0; j < CP8; ++j) gE[0][j] = *(const us8v*)(gp + uo[j]);
        }
        if (cnt >= 2) {
            const unsigned short* gp = G + (size_t)s1 * ROWG;
#pragma unroll
            for (int j = 0; j < CP8; ++j) gE[1][j] = *(const us8v*)(gp + uo[j]);
        }
        if (cnt >= 3) {
            const unsigned short* gp = G + (size_t)s2 * ROWG;
#pragma unroll
            for (int j = 0; j < CP8; ++j) gE[2][j] = *(const us8v*)(gp + uo[j]);
        }
        if (cnt >= 4) {
            const unsigned short* gp = G + (size_t)s3 * ROWG;
#pragma unroll
            for (int j = 0; j < CP8; ++j) gE[3][j] = *(const us8v*)(gp + uo[j]);
        }
        if (NIT > 1) {
            const int so1 = smO[mb + NRC];
            sx[0] = ssrc[so1]; sx[1] = ssrc[so1 + 1];
            sx[2] = ssrc[so1 + 2]; sx[3] = ssrc[so1 + 3];
        }
    }

    // B fragments for it=0 (fragment-major: contiguous 1 KB per load)
    bf8v bfr[2][KT];
    {
#pragma unroll
        for (int ct = 0; ct < 2; ++ct) {
#pragma unroll
            for (int ks = 0; ks < KT; ++ks)
                bfr[ct][ks] = *(const bf8v*)(Bw + ((size_t)ks * 8 + cb16 + ct) * 512 + fo);
        }
    }

#pragma unroll 2
    for (int it = 0; it < NIT; ++it) {
        unsigned short* Ab = As[it & 1];
        // ---- gather (per-j streaming, packed-pair math) ----
        {
            const int so = smO[mb + it * NRC], eo = smO[mb + it * NRC + 1];
            const int cnt = eo - so;
            const float m2 = cnt >= 2 ? 1.f : 0.f;
            const float m3 = cnt >= 3 ? 1.f : 0.f;
            const float m4 = cnt >= 4 ? 1.f : 0.f;
            const f2v m2v = {m2, m2}, m3v = {m3, m3}, m4v = {m4, m4};
            const float iv = smI[mbI + it * NRC];
            const f2v iv2 = {iv, iv};
            unsigned short* wp = &Ab[lbase];
#pragma unroll
            for (int j = 0; j < CP8; ++j) {
                const ui4v e0 = __builtin_bit_cast(ui4v, gE[0][j]);
                const ui4v e1 = __builtin_bit_cast(ui4v, gE[1][j]);
                const ui4v e2 = __builtin_bit_cast(ui4v, gE[2][j]);
                const ui4v e3 = __builtin_bit_cast(ui4v, gE[3][j]);
                f2v aj[4];
#pragma unroll
                for (int p2 = 0; p2 < 4; ++p2)
                    aj[p2] = up2(e0[p2]) + m2v * up2(e1[p2])
                           + m3v * up2(e2[p2]) + m4v * up2(e3[p2]);
                for (int p = so + 4; p < eo; ++p) {     // rare tail (P ~2e-3)
                    const unsigned short* gp = G + (size_t)ssrc[p] * ROWG;
                    ui4v g = __builtin_bit_cast(ui4v, *(const us8v*)(gp + uo[j]));
#pragma unroll
                    for (int p2 = 0; p2 < 4; ++p2) aj[p2] += up2(g[p2]);
                }
                us8v sv;
#pragma unroll
                for (int p2 = 0; p2 < 4; ++p2) {
                    f2v s = aj[p2] * iv2;
                    sv[2 * p2]     = f2b(s[0]);
                    sv[2 * p2 + 1] = f2b(s[1]);
                }
                *(us8v*)(wp + uo[j]) = sv;
            }

            // pre-barrier: issue it+1's staged edges + srcs for it+2
            if (it + 1 < NIT) {
                const int b1o = mb + (it + 1) * NRC;
                const int c1 = smO[b1o + 1] - smO[b1o];
                if (c1 >= 1) {
                    const unsigned short* gp = G + (size_t)sx[0] * ROWG;
#pragma unroll
                    for (int j = 0; j < CP8; ++j) gE[0][j] = *(const us8v*)(gp + uo[j]);
                }
                if (c1 >= 2) {
                    const unsigned short* gp = G + (size_t)sx[1] * ROWG;
#pragma unroll
                    for (int j = 0; j < CP8; ++j) gE[1][j] = *(const us8v*)(gp + uo[j]);
                }
                if (c1 >= 3) {
                    const unsigned short* gp = G + (size_t)sx[2] * ROWG;
#pragma unroll
                    for (int j = 0; j < CP8; ++j) gE[2][j] = *(const us8v*)(gp + uo[j]);
                }
                if (c1 >= 4) {
                    const unsigned short* gp = G + (size_t)sx[3] * ROWG;
#pragma unroll
                    for (int j = 0; j < CP8; ++j) gE[3][j] = *(const us8v*)(gp + uo[j]);
                }
                if (it + 2 < NIT) {
                    const int so2 = smO[mb + (it + 2) * NRC];
                    sx[0] = ssrc[so2]; sx[1] = ssrc[so2 + 1];
                    sx[2] = ssrc[so2 + 2]; sx[3] = ssrc[so2 + 3];
                }
            }
        }
        lds_barrier();   // LDS-only drain: global prefetches stay in flight

        // ---- A fragments + MFMA (setprio: favor MFMA waves on the CU) ----
        __builtin_amdgcn_s_setprio(1);
#pragma unroll
        for (int rt = 0; rt < RT; ++rt) {
            const unsigned short* ar = &Ab[(m16 + 16 * rt) * LSS];
#pragma unroll
            for (int ks = 0; ks < KT; ++ks) {
                bf8v af = *(const bf8v*)(ar + ks * 32 + q * 8);
                acc[rt][0] = __builtin_amdgcn_mfma_f32_16x16x32_bf16(af, bfr[0][ks], acc[rt][0], 0, 0, 0);
                acc[rt][1] = __builtin_amdgcn_mfma_f32_16x16x32_bf16(af, bfr[1][ks], acc[rt][1], 0, 0, 0);
            }
        }
        __builtin_amdgcn_s_setprio(0);

        // ---- B fragments for it+1 (root weights after the last iteration) ----
        if (it + 1 < NIT) {
            const int kb0 = ((it + 1) * NRC * ROWG) >> 5;
#pragma unroll
            for (int ct = 0; ct < 2; ++ct) {
#pragma unroll
                for (int ks = 0; ks < KT; ++ks)
                    bfr[ct][ks] = *(const bf8v*)(Bw + ((size_t)(kb0 + ks) * 8 + cb16 + ct) * 512 + fo);
            }
        } else {
#pragma unroll
            for (int ct = 0; ct < 2; ++ct) {
#pragma unroll
                for (int ks = 0; ks < KR; ++ks)
                    bfr[ct][ks] = *(const bf8v*)(Br + ((size_t)ks * 8 + cb16 + ct) * 512 + fo);
            }
        }
    }

    // ---- root transform: A straight from global ----
    {
#pragma unroll
        for (int rt = 0; rt < RT; ++rt) {
            const unsigned short* gr = G + (size_t)(d0 + m16 + 16 * rt) * ROWG;
#pragma unroll
            for (int ks = 0; ks < KR; ++ks) {
                bf8v af;
                if constexpr (ROWG % 32 == 0) {
                    af = *(const bf8v*)(gr + ks * 32 + q * 8);
                } else {
                    // partial K-block (layer 1: ROWG=16, KR=1): upper lanes zero
                    af = bf8v{0, 0, 0, 0, 0, 0, 0, 0};
                    if (ks * 32 + q * 8 + 8 <= ROWG)
                        af = *(const bf8v*)(gr + ks * 32 + q * 8);
                }
                acc[rt][0] = __builtin_amdgcn_mfma_f32_16x16x32_bf16(af, bfr[0][ks], acc[rt][0], 0, 0, 0);
                acc[rt][1] = __builtin_amdgcn_mfma_f32_16x16x32_bf16(af, bfr[1][ks], acc[rt][1], 0, 0, 0);
            }
        }
    }

    if constexpr (OUT == 1) {
        // ---- fused epilogue (layer 1): bias + ReLU + bf16 -> fout ----
#pragma unroll
        for (int ct = 0; ct < 2; ++ct) {
            const int col = colb + 16 * ct + m16;
            const float bb = bias[col];
#pragma unroll
            for (int rt = 0; rt < RT; ++rt) {
#pragma unroll
                for (int g = 0; g < 4; ++g) {
                    const int rr = 16 * rt + q * 4 + g;
                    fout[(size_t)(d0 + rr) * HID + col] =
                        f2b(fmaxf(acc[rt][ct][g] + bb, 0.0f));
                }
            }
        }
    } else {
        // ---- fused epilogue (layer 2): bias + fp32 -> outf (final output) ----
#pragma unroll
        for (int ct = 0; ct < 2; ++ct) {
            const int col = colb + 16 * ct + m16;
            const float bb = bias[col];
#pragma unroll
            for (int rt = 0; rt < RT; ++rt) {
#pragma unroll
                for (int g = 0; g < 4; ++g) {
                    const int rr = 16 * rt + q * 4 + g;
                    outf[(size_t)(d0 + rr) * HID + col] = acc[rt][ct][g] + bb;
                }
            }
        }
    }
}

// Distinct names so rocprof attributes layer 1 vs layer 2 separately.
__global__ __launch_bounds__(256) void gemm_l1(
    const int* __restrict__ binoff, const int* __restrict__ bbase,
    const float* __restrict__ inv, const int* __restrict__ ssrc,
    const unsigned short* __restrict__ G, const unsigned short* __restrict__ Bw,
    const unsigned short* __restrict__ Br,
    unsigned short* __restrict__ fout, const float* __restrict__ bias) {
    // NRC=4 -> NCH=2: lane pairs cover one contiguous 32 B row (TA line-work /2)
    gemm_body<32, 16, 4, 8, 1, 1>(binoff, bbase, inv, ssrc, G, Bw, Br,
                                  nullptr, fout, bias);
}

__global__ __launch_bounds__(256) void gemm_l2(
    const int* __restrict__ binoff, const int* __restrict__ bbase,
    const float* __restrict__ inv, const int* __restrict__ ssrc,
    const unsigned short* __restrict__ G, const unsigned short* __restrict__ Bw,
    const unsigned short* __restrict__ Br,
    float* __restrict__ outf, const float* __restrict__ bias) {
    gemm_body<32, 128, 1, 32, 4, 2>(binoff, bbase, inv, ssrc, G, Bw, Br,
                                    outf, nullptr, bias);
}

extern "C" void kernel_launch(void* const* d_in, const int* in_sizes, int n_in,
                              void* d_out, int out_size, void* d_ws, size_t ws_size,
                              hipStream_t stream) {
    const int*   ei    = (const int*)d_in[0];   // [2, E]
    const int*   et    = (const int*)d_in[1];   // [E]
    const float* x     = (const float*)d_in[2]; // [N, 16]
    const float* W1    = (const float*)d_in[3]; // [32, 16, 128]
    const float* root1 = (const float*)d_in[4]; // [16, 128]
    const float* b1    = (const float*)d_in[5]; // [128]
    const float* W2    = (const float*)d_in[6]; // [32, 128, 128]
    const float* root2 = (const float*)d_in[7]; // [128, 128]
    const float* b2    = (const float*)d_in[8]; // [128]
    float* out = (float*)d_out;

    // ---- workspace layout (~16 MB) ----
    char* ws = (char*)d_ws;
    size_t off = 0;
    auto alloc = [&](size_t bytes) { void* p = ws + off; off = (off + bytes + 63) & ~(size_t)63; return p; };
    int*   hist    = (int*)  alloc((size_t)NB * 4);
    int*   binoff  = (int*)  alloc((size_t)(NB + 1) * 4);
    int*   cursors = (int*)  alloc((size_t)NB * 4);
    float* inv     = (float*)alloc((size_t)NB * 4);
    int*   bsum    = (int*)  alloc(625 * 4);
    int*   bbase   = (int*)  alloc(626 * 4);
    int*   ssrc    = (int*)  alloc((size_t)(N_EDGES + 4) * 4);
    unsigned short* xb  = (unsigned short*)alloc((size_t)N_NODES * EMB * 2);
    unsigned short* h1b = (unsigned short*)alloc((size_t)N_NODES * HID * 2);
    unsigned short* w1t = (unsigned short*)alloc((size_t)N_REL * EMB * HID * 2);
    unsigned short* r1t = (unsigned short*)alloc((size_t)HID * 32 * 2);
    unsigned short* w2t = (unsigned short*)alloc((size_t)N_REL * HID * HID * 2);
    unsigned short* r2t = (unsigned short*)alloc((size_t)HID * HID * 2);

    const int* src = ei;
    const int* dst = ei + N_EDGES;

    hipMemsetAsync(hist, 0, (size_t)NB * 4, stream);
    pre1_k<<<(PRE_TOT + 255) / 256, 256, 0, stream>>>(
        dst, et, x, W1, root1, W2, root2, hist, xb, w1t, r1t, w2t, r2t);
    scan1_k<<<NB / 1024, 256, 0, stream>>>(hist, binoff, cursors, bsum, inv);
    scan2_k<<<1, 1024, 0, stream>>>(bsum, bbase, binoff);
    scatter_k<<<(N_EDGES / 2 + 255) / 256, 256, 0, stream>>>(src, dst, et, cursors, bbase, ssrc);

    // ---- layer 1: 32-row tiles (625 blocks), 4 rels/iter (K=64), NCH=2
    //      coalesced row-pair gather; 8 iterations + root; bias+ReLU -> h1b ----
    gemm_l1<<<dim3(625, 1), 256, 0, stream>>>(
        binoff, bbase, inv, ssrc, xb, w1t, r1t, h1b, b1);

    // ---- layer 2: 32-row tiles (625 blocks), 1 rel/iter (K=128),
    //      32 iterations + root, 1-deep staging (R2 optimum); bias -> out ----
    gemm_l2<<<dim3(625, 1), 256, 0, stream>>>(
        binoff, bbase, inv, ssrc, h1b, w2t, r2t, out, b2);
}